// Round 1
// baseline (309.136 us; speedup 1.0000x reference)
//
#include <hip/hip_runtime.h>
#include <math.h>

constexpr int B_ = 256;
constexpr int D_ = 128;
constexpr int N_ = 65536;
constexpr int P_ = 100;
constexpr int K_ = 4096;
constexpr int P2_ = 10;
constexpr int KP_ = K_ + P_;       // 4196
constexpr int OC_ = P2_ + K_;      // 4106
constexpr int SPLIT_ = 8;
constexpr int NBLK_ = B_ * SPLIT_; // 2048
constexpr float T_ = 0.07f;

// ---------------- kernel 1: gathered dot products ----------------
// grid = B*SPLIT blocks of 256 (4 waves). Each wave reduces one gathered row
// (float2/lane, 64 lanes = 128 elems) via butterfly shuffles.
__global__ __launch_bounds__(256) void k_dots(
    const float* __restrict__ v1, const float* __restrict__ v2,
    const int* __restrict__ idx, const float* __restrict__ mem1,
    const float* __restrict__ mem2, float* __restrict__ out,
    double* __restrict__ wdiff, float* __restrict__ woutp,
    double* __restrict__ wpart)
{
  const int b = blockIdx.x / SPLIT_;
  const int s = blockIdx.x % SPLIT_;
  const int tid = threadIdx.x;
  const int wave = tid >> 6;
  const int lane = tid & 63;
  constexpr int CH = (KP_ + SPLIT_ - 1) / SPLIT_;  // 525
  const int base = s * CH;
  const int end = (base + CH < KP_) ? (base + CH) : KP_;

  const float2 v1v = *reinterpret_cast<const float2*>(v1 + (size_t)b * D_ + lane * 2);
  const float2 v2v = *reinterpret_cast<const float2*>(v2 + (size_t)b * D_ + lane * 2);

  // f64 norms of v1,v2 (used only on the k<P cosine path; cheap one-time)
  double dn1 = (double)v1v.x * v1v.x + (double)v1v.y * v1v.y;
  double dn2 = (double)v2v.x * v2v.x + (double)v2v.y * v2v.y;
#pragma unroll
  for (int sh = 1; sh < 64; sh <<= 1) {
    dn1 += __shfl_xor(dn1, sh);
    dn2 += __shfl_xor(dn2, sh);
  }
  const double inv_nv1 = 1.0 / sqrt(dn1);
  const double inv_nv2 = 1.0 / sqrt(dn2);

  const int* idxb = idx + (size_t)b * KP_;
  double acc = 0.0;  // lane0-only accumulation of exp values (k >= P)

  for (int r = base + wave; r < end; r += 4) {
    const int row = idxb[r];
    const float2 w1 = *reinterpret_cast<const float2*>(mem1 + (size_t)row * D_ + lane * 2);
    if (r >= P_) {
      float d = w1.x * v2v.x + w1.y * v2v.y;
#pragma unroll
      for (int sh = 1; sh < 64; sh <<= 1) d += __shfl_xor(d, sh);
      const float e = expf(d * (1.0f / T_));
      if (lane == 0) {
        out[(size_t)b * OC_ + P2_ + (r - P_)] = e;  // unnormalized; scaled later
        acc += (double)e;
      }
    } else {
      // cosine-sim diff path: f64 for robust ordering in the top-10 selection
      const float2 w2 = *reinterpret_cast<const float2*>(mem2 + (size_t)row * D_ + lane * 2);
      double so  = (double)w1.x * v2v.x + (double)w1.y * v2v.y;
      double sn1 = (double)w1.x * w1.x + (double)w1.y * w1.y;
      double st  = (double)w1.x * v1v.x + (double)w1.y * v1v.y;
      double sn2 = (double)w2.x * w2.x + (double)w2.y * w2.y;
      double ss  = (double)w2.x * v2v.x + (double)w2.y * v2v.y;
#pragma unroll
      for (int sh = 1; sh < 64; sh <<= 1) {
        so  += __shfl_xor(so, sh);
        sn1 += __shfl_xor(sn1, sh);
        st  += __shfl_xor(st, sh);
        sn2 += __shfl_xor(sn2, sh);
        ss  += __shfl_xor(ss, sh);
      }
      if (lane == 0) {
        const double t_rel = st * inv_nv1 / sqrt(sn1);
        const double s_rel = ss * inv_nv2 / sqrt(sn2);
        wdiff[b * P_ + r] = t_rel - s_rel;
        woutp[b * P_ + r] = expf((float)(so * (1.0 / (double)T_)));
      }
    }
  }

  __shared__ double lacc[4];
  if (lane == 0) lacc[wave] = acc;
  __syncthreads();
  if (tid == 0) wpart[blockIdx.x] = (lacc[0] + lacc[1]) + (lacc[2] + lacc[3]);
}

// ---------------- kernel 2: stable top-10 selection per row ----------------
// jnp.argsort(-diff) is stable: descending value, ties -> smaller index first.
// Iterative argmax with strict '>' reproduces that exactly.
__global__ __launch_bounds__(128) void k_select(
    const double* __restrict__ wdiff, const float* __restrict__ woutp,
    float* __restrict__ out, double* __restrict__ wpart)
{
  __shared__ double sdiff[P_];
  const int b = blockIdx.x;
  const int tid = threadIdx.x;
  if (tid < P_) sdiff[tid] = wdiff[b * P_ + tid];
  __syncthreads();
  if (tid == 0) {
    unsigned long long lo = 0ull, hi = 0ull;  // taken bitmask (100 bits)
    int sel[P2_];
#pragma unroll
    for (int t = 0; t < P2_; ++t) {
      double best = -1e300;
      int bj = 0;
      for (int j = 0; j < P_; ++j) {
        const bool tk = (j < 64) ? ((lo >> j) & 1ull) : ((hi >> (j - 64)) & 1ull);
        const double v = sdiff[j];
        if (!tk && v > best) { best = v; bj = j; }
      }
      sel[t] = bj;
      if (bj < 64) lo |= (1ull << bj); else hi |= (1ull << (bj - 64));
    }
    sel[0] = 0;  // .at[:,0].set(0) applied AFTER taking top-P2
    double sp = 0.0;
#pragma unroll
    for (int t = 0; t < P2_; ++t) {
      const float e = woutp[b * P_ + sel[t]];
      out[(size_t)b * OC_ + t] = e;  // unnormalized
      sp += (double)e;
    }
    wpart[NBLK_ + b] = sp;
  }
}

// ---------------- kernel 3: reduce partials -> 1/Z ----------------
__global__ __launch_bounds__(256) void k_z(
    const double* __restrict__ wpart, float* __restrict__ invz)
{
  __shared__ double lds[4];
  const int tid = threadIdx.x;
  double s = 0.0;
  for (int i = tid; i < NBLK_ + B_; i += 256) s += wpart[i];
#pragma unroll
  for (int sh = 1; sh < 64; sh <<= 1) s += __shfl_xor(s, sh);
  if ((tid & 63) == 0) lds[tid >> 6] = s;
  __syncthreads();
  if (tid == 0) {
    const double S = (lds[0] + lds[1]) + (lds[2] + lds[3]);
    const double Z = S / ((double)B_ * (double)OC_) * (double)N_;
    *invz = (float)(1.0 / Z);
  }
}

// ---------------- kernel 4: scale score region by 1/Z ----------------
__global__ __launch_bounds__(256) void k_scale(
    float* __restrict__ out, const float* __restrict__ invz)
{
  const size_t i = (size_t)blockIdx.x * blockDim.x + threadIdx.x;
  constexpr size_t n4 = (size_t)B_ * OC_ / 4;  // 262784, exact
  if (i < n4) {
    const float sc = *invz;
    float4 v = reinterpret_cast<float4*>(out)[i];
    v.x *= sc; v.y *= sc; v.z *= sc; v.w *= sc;
    reinterpret_cast<float4*>(out)[i] = v;
  }
}

// ---------------- kernel 5: copy memory_v1 -> output ----------------
__global__ __launch_bounds__(256) void k_copy(
    const float* __restrict__ src, float* __restrict__ dst)
{
  const size_t i = ((size_t)blockIdx.x * blockDim.x + threadIdx.x) * 4;
  const float4 v = *reinterpret_cast<const float4*>(src + i);
  *reinterpret_cast<float4*>(dst + i) = v;
}

// ---------------- kernel 6: update + normalize rows y ----------------
__global__ __launch_bounds__(64) void k_update(
    const float* __restrict__ mem1, const float* __restrict__ v1,
    const int* __restrict__ y, float* __restrict__ dst)
{
  const int b = blockIdx.x;
  const int lane = threadIdx.x;
  const int row = y[b];
  const float2 m = *reinterpret_cast<const float2*>(mem1 + (size_t)row * D_ + lane * 2);
  const float2 a = *reinterpret_cast<const float2*>(v1 + (size_t)b * D_ + lane * 2);
  float2 l;
  l.x = m.x * 0.5f + a.x * 0.5f;
  l.y = m.y * 0.5f + a.y * 0.5f;
  float n = l.x * l.x + l.y * l.y;
#pragma unroll
  for (int sh = 1; sh < 64; sh <<= 1) n += __shfl_xor(n, sh);
  const float inv = 1.0f / sqrtf(n);
  float2 o;
  o.x = l.x * inv;
  o.y = l.y * inv;
  *reinterpret_cast<float2*>(dst + (size_t)row * D_ + lane * 2) = o;
}

extern "C" void kernel_launch(void* const* d_in, const int* in_sizes, int n_in,
                              void* d_out, int out_size, void* d_ws, size_t ws_size,
                              hipStream_t stream) {
  // setup_inputs order: epoch, v1, v2, y, idx, memory_v1, memory_v2
  const float* v1   = (const float*)d_in[1];
  const float* v2   = (const float*)d_in[2];
  const int*   y    = (const int*)d_in[3];
  const int*   idx  = (const int*)d_in[4];
  const float* mem1 = (const float*)d_in[5];
  const float* mem2 = (const float*)d_in[6];

  float* out    = (float*)d_out;                      // (B, P2+K) scores
  float* outmem = out + (size_t)B_ * OC_;             // (N, D) new memory

  char* ws = (char*)d_ws;
  double* wpart = (double*)ws;                                   // NBLK_+B_ doubles (18,432 B used of 2304*8)
  double* wdiff = (double*)(ws + 32768);                         // B*P doubles = 204,800 B
  float*  woutp = (float*)(ws + 32768 + 204800);                 // B*P floats  = 102,400 B
  float*  invz  = (float*)(ws + 32768 + 204800 + 102400);        // 1 float

  k_dots<<<NBLK_, 256, 0, stream>>>(v1, v2, idx, mem1, mem2, out, wdiff, woutp, wpart);
  k_select<<<B_, 128, 0, stream>>>(wdiff, woutp, out, wpart);
  k_z<<<1, 256, 0, stream>>>(wpart, invz);
  {
    constexpr int n4 = B_ * OC_ / 4;
    k_scale<<<(n4 + 255) / 256, 256, 0, stream>>>(out, invz);
  }
  k_copy<<<(N_ * D_) / (256 * 4), 256, 0, stream>>>(mem1, outmem);  // 8192 blocks
  k_update<<<B_, 64, 0, stream>>>(mem1, v1, y, outmem);
}

// Round 2
// 169.562 us; speedup vs baseline: 1.8231x; 1.8231x over previous
//
#include <hip/hip_runtime.h>
#include <math.h>

constexpr int B_ = 256;
constexpr int D_ = 128;
constexpr int N_ = 65536;
constexpr int P_ = 100;
constexpr int K_ = 4096;
constexpr int P2_ = 10;
constexpr int KP_ = K_ + P_;       // 4196
constexpr int OC_ = P2_ + K_;      // 4106
constexpr int NNEG_ = B_ * (K_ / 256);   // 4096 blocks, 256 rows each
constexpr int NPART_ = NNEG_ + B_;       // partial-sum slots
constexpr float T_ = 0.07f;

// ---------------- kernel 1: gathered dots (one thread per row) ----------------
// Blocks [0, NNEG_): negatives. b = blk>>4, 256 rows/block, 1 row/thread.
//   Row loaded as 32 x float4 (16 staged at a time -> 16 outstanding loads),
//   v2 read from LDS at uniform addresses (broadcast, conflict-free), no shuffles.
// Blocks [NNEG_, NNEG_+B_): cosine path for r < P, 1 row/thread, f64 dots.
__global__ __launch_bounds__(256) void k_gather(
    const float* __restrict__ v1, const float* __restrict__ v2,
    const int* __restrict__ idx, const float* __restrict__ mem1,
    const float* __restrict__ mem2, float* __restrict__ out,
    double* __restrict__ wdiff, float* __restrict__ woutp,
    double* __restrict__ wpart)
{
  const int tid = threadIdx.x;
  __shared__ float sbuf[2 * D_];
  if (blockIdx.x < NNEG_) {
    const int b = blockIdx.x >> 4;
    const int c = blockIdx.x & 15;
    if (tid < 32)
      reinterpret_cast<float4*>(sbuf)[tid] =
          reinterpret_cast<const float4*>(v2 + (size_t)b * D_)[tid];
    __syncthreads();
    const int rk = (c << 8) + tid;                       // 0..4095
    const int row = idx[(size_t)b * KP_ + P_ + rk];
    const float4* __restrict__ wp = reinterpret_cast<const float4*>(mem1 + (size_t)row * D_);
    const float4* __restrict__ s4 = reinterpret_cast<const float4*>(sbuf);
    float acc = 0.0f;
    float4 w[16];
#pragma unroll
    for (int j = 0; j < 16; ++j) w[j] = wp[j];
#pragma unroll
    for (int j = 0; j < 16; ++j) {
      const float4 x = s4[j];
      acc += w[j].x * x.x + w[j].y * x.y + w[j].z * x.z + w[j].w * x.w;
    }
#pragma unroll
    for (int j = 0; j < 16; ++j) w[j] = wp[16 + j];
#pragma unroll
    for (int j = 0; j < 16; ++j) {
      const float4 x = s4[16 + j];
      acc += w[j].x * x.x + w[j].y * x.y + w[j].z * x.z + w[j].w * x.w;
    }
    const float e = expf(acc * (1.0f / T_));
    out[(size_t)b * OC_ + P2_ + rk] = e;                 // unnormalized; scaled later
    // block sum of e (f64) -> wpart[blockIdx]
    double de = (double)e;
#pragma unroll
    for (int sh = 1; sh < 64; sh <<= 1) de += __shfl_xor(de, sh);
    __shared__ double lacc[4];
    if ((tid & 63) == 0) lacc[tid >> 6] = de;
    __syncthreads();
    if (tid == 0) wpart[blockIdx.x] = (lacc[0] + lacc[1]) + (lacc[2] + lacc[3]);
  } else {
    const int b = blockIdx.x - NNEG_;
    if (tid < 32)
      reinterpret_cast<float4*>(sbuf)[tid] =             // sbuf[0..127] = v2[b]
          reinterpret_cast<const float4*>(v2 + (size_t)b * D_)[tid];
    else if (tid < 64)
      reinterpret_cast<float4*>(sbuf)[tid] =             // sbuf[128..255] = v1[b]
          reinterpret_cast<const float4*>(v1 + (size_t)b * D_)[tid - 32];
    __syncthreads();
    if (tid < P_) {
      double n2a = 0.0, n2b = 0.0, n1a = 0.0, n1b = 0.0;
#pragma unroll 8
      for (int j = 0; j < D_; j += 2) {
        n2a += (double)sbuf[j] * sbuf[j];
        n2b += (double)sbuf[j + 1] * sbuf[j + 1];
        n1a += (double)sbuf[D_ + j] * sbuf[D_ + j];
        n1b += (double)sbuf[D_ + j + 1] * sbuf[D_ + j + 1];
      }
      const double inv_n1 = 1.0 / sqrt(n1a + n1b);
      const double inv_n2 = 1.0 / sqrt(n2a + n2b);
      const int row = idx[(size_t)b * KP_ + tid];
      const float4* __restrict__ w1p = reinterpret_cast<const float4*>(mem1 + (size_t)row * D_);
      const float4* __restrict__ w2p = reinterpret_cast<const float4*>(mem2 + (size_t)row * D_);
      const float4* __restrict__ x2p = reinterpret_cast<const float4*>(sbuf);
      const float4* __restrict__ x1p = reinterpret_cast<const float4*>(sbuf + D_);
      double so = 0, sn1 = 0, st = 0, sn2 = 0, ss = 0;
#pragma unroll 4
      for (int j = 0; j < 32; ++j) {
        const float4 a  = w1p[j];
        const float4 cc = w2p[j];
        const float4 x1 = x1p[j];
        const float4 x2 = x2p[j];
        so  += (double)a.x * x2.x + (double)a.y * x2.y + (double)a.z * x2.z + (double)a.w * x2.w;
        sn1 += (double)a.x * a.x  + (double)a.y * a.y  + (double)a.z * a.z  + (double)a.w * a.w;
        st  += (double)a.x * x1.x + (double)a.y * x1.y + (double)a.z * x1.z + (double)a.w * x1.w;
        sn2 += (double)cc.x * cc.x + (double)cc.y * cc.y + (double)cc.z * cc.z + (double)cc.w * cc.w;
        ss  += (double)cc.x * x2.x + (double)cc.y * x2.y + (double)cc.z * x2.z + (double)cc.w * x2.w;
      }
      const double t_rel = st * inv_n1 / sqrt(sn1);
      const double s_rel = ss * inv_n2 / sqrt(sn2);
      wdiff[b * P_ + tid] = t_rel - s_rel;
      woutp[b * P_ + tid] = expf((float)(so * (1.0 / (double)T_)));
    }
  }
}

// ---------------- kernel 2: stable top-10 selection per row ----------------
// jnp.argsort(-diff) is stable: descending value, ties -> smaller index first.
// Iterative argmax with strict '>' reproduces that exactly.
__global__ __launch_bounds__(128) void k_select(
    const double* __restrict__ wdiff, const float* __restrict__ woutp,
    float* __restrict__ out, double* __restrict__ wpart)
{
  __shared__ double sdiff[P_];
  const int b = blockIdx.x;
  const int tid = threadIdx.x;
  if (tid < P_) sdiff[tid] = wdiff[b * P_ + tid];
  __syncthreads();
  if (tid == 0) {
    unsigned long long lo = 0ull, hi = 0ull;  // taken bitmask (100 bits)
    int sel[P2_];
#pragma unroll
    for (int t = 0; t < P2_; ++t) {
      double best = -1e300;
      int bj = 0;
      for (int j = 0; j < P_; ++j) {
        const bool tk = (j < 64) ? ((lo >> j) & 1ull) : ((hi >> (j - 64)) & 1ull);
        const double v = sdiff[j];
        if (!tk && v > best) { best = v; bj = j; }
      }
      sel[t] = bj;
      if (bj < 64) lo |= (1ull << bj); else hi |= (1ull << (bj - 64));
    }
    sel[0] = 0;  // .at[:,0].set(0) applied AFTER taking top-P2
    double sp = 0.0;
#pragma unroll
    for (int t = 0; t < P2_; ++t) {
      const float e = woutp[b * P_ + sel[t]];
      out[(size_t)b * OC_ + t] = e;  // unnormalized
      sp += (double)e;
    }
    wpart[NNEG_ + b] = sp;
  }
}

// ---------------- kernel 3: reduce partials -> 1/Z ----------------
__global__ __launch_bounds__(256) void k_z(
    const double* __restrict__ wpart, float* __restrict__ invz)
{
  __shared__ double lds[4];
  const int tid = threadIdx.x;
  double s = 0.0;
  for (int i = tid; i < NPART_; i += 256) s += wpart[i];
#pragma unroll
  for (int sh = 1; sh < 64; sh <<= 1) s += __shfl_xor(s, sh);
  if ((tid & 63) == 0) lds[tid >> 6] = s;
  __syncthreads();
  if (tid == 0) {
    const double S = (lds[0] + lds[1]) + (lds[2] + lds[3]);
    const double Z = S / ((double)B_ * (double)OC_) * (double)N_;
    *invz = (float)(1.0 / Z);
  }
}

// ---------------- kernel 4: scale score region by 1/Z ----------------
__global__ __launch_bounds__(256) void k_scale(
    float* __restrict__ out, const float* __restrict__ invz)
{
  const size_t i = (size_t)blockIdx.x * blockDim.x + threadIdx.x;
  constexpr size_t n4 = (size_t)B_ * OC_ / 4;  // 262784, exact
  if (i < n4) {
    const float sc = *invz;
    float4 v = reinterpret_cast<float4*>(out)[i];
    v.x *= sc; v.y *= sc; v.z *= sc; v.w *= sc;
    reinterpret_cast<float4*>(out)[i] = v;
  }
}

// ---------------- kernel 5: copy memory_v1 -> output ----------------
__global__ __launch_bounds__(256) void k_copy(
    const float* __restrict__ src, float* __restrict__ dst)
{
  const size_t i = ((size_t)blockIdx.x * blockDim.x + threadIdx.x) * 4;
  const float4 v = *reinterpret_cast<const float4*>(src + i);
  *reinterpret_cast<float4*>(dst + i) = v;
}

// ---------------- kernel 6: update + normalize rows y ----------------
__global__ __launch_bounds__(64) void k_update(
    const float* __restrict__ mem1, const float* __restrict__ v1,
    const int* __restrict__ y, float* __restrict__ dst)
{
  const int b = blockIdx.x;
  const int lane = threadIdx.x;
  const int row = y[b];
  const float2 m = *reinterpret_cast<const float2*>(mem1 + (size_t)row * D_ + lane * 2);
  const float2 a = *reinterpret_cast<const float2*>(v1 + (size_t)b * D_ + lane * 2);
  float2 l;
  l.x = m.x * 0.5f + a.x * 0.5f;
  l.y = m.y * 0.5f + a.y * 0.5f;
  float n = l.x * l.x + l.y * l.y;
#pragma unroll
  for (int sh = 1; sh < 64; sh <<= 1) n += __shfl_xor(n, sh);
  const float inv = 1.0f / sqrtf(n);
  float2 o;
  o.x = l.x * inv;
  o.y = l.y * inv;
  *reinterpret_cast<float2*>(dst + (size_t)row * D_ + lane * 2) = o;
}

extern "C" void kernel_launch(void* const* d_in, const int* in_sizes, int n_in,
                              void* d_out, int out_size, void* d_ws, size_t ws_size,
                              hipStream_t stream) {
  // setup_inputs order: epoch, v1, v2, y, idx, memory_v1, memory_v2
  const float* v1   = (const float*)d_in[1];
  const float* v2   = (const float*)d_in[2];
  const int*   y    = (const int*)d_in[3];
  const int*   idx  = (const int*)d_in[4];
  const float* mem1 = (const float*)d_in[5];
  const float* mem2 = (const float*)d_in[6];

  float* out    = (float*)d_out;                      // (B, P2+K) scores
  float* outmem = out + (size_t)B_ * OC_;             // (N, D) new memory

  char* ws = (char*)d_ws;
  double* wpart = (double*)ws;                                   // NPART_ doubles
  double* wdiff = (double*)(ws + 65536);                         // B*P doubles = 204,800 B
  float*  woutp = (float*)(ws + 65536 + 204800);                 // B*P floats  = 102,400 B
  float*  invz  = (float*)(ws + 65536 + 204800 + 102400);        // 1 float

  k_gather<<<NNEG_ + B_, 256, 0, stream>>>(v1, v2, idx, mem1, mem2,
                                           out, wdiff, woutp, wpart);
  k_select<<<B_, 128, 0, stream>>>(wdiff, woutp, out, wpart);
  k_z<<<1, 256, 0, stream>>>(wpart, invz);
  {
    constexpr int n4 = B_ * OC_ / 4;
    k_scale<<<(n4 + 255) / 256, 256, 0, stream>>>(out, invz);
  }
  k_copy<<<(N_ * D_) / (256 * 4), 256, 0, stream>>>(mem1, outmem);  // 8192 blocks
  k_update<<<B_, 64, 0, stream>>>(mem1, v1, y, outmem);
}

// Round 3
// 149.926 us; speedup vs baseline: 2.0619x; 1.1310x over previous
//
#include <hip/hip_runtime.h>
#include <math.h>

constexpr int B_ = 256;
constexpr int D_ = 128;
constexpr int N_ = 65536;
constexpr int P_ = 100;
constexpr int K_ = 4096;
constexpr int P2_ = 10;
constexpr int KP_ = K_ + P_;       // 4196
constexpr int OC_ = P2_ + K_;      // 4106
constexpr int NNEG_ = B_ * (K_ / 256);   // 4096 blocks, 256 rows each
constexpr int NPART_ = NNEG_ + B_;       // partial-sum slots
constexpr float T_ = 0.07f;

// ---------------- kernel 1: gathered dots (8 lanes per row) ----------------
// Blocks [0, NNEG_): negatives. b = blk>>4, 256 rows/block.
//   Each wave: 8 rows at a time (8 lanes/row). Lane j of group g loads the
//   aligned 128B line chunks of its row as float4s -> 8 lines/instr (vs 64
//   for one-thread-per-row). v2 fragment kept in registers. 3-step shuffle
//   reduce within the 8-lane group. 2 row-batches in flight for MLP.
// Blocks [NNEG_, NNEG_+B_): cosine path for r < P, 1 row/thread, f64 dots.
__global__ __launch_bounds__(256) void k_gather(
    const float* __restrict__ v1, const float* __restrict__ v2,
    const int* __restrict__ idx, const float* __restrict__ mem1,
    const float* __restrict__ mem2, float* __restrict__ out,
    double* __restrict__ wdiff, float* __restrict__ woutp,
    double* __restrict__ wpart)
{
  const int tid = threadIdx.x;
  if (blockIdx.x < NNEG_) {
    const int b = blockIdx.x >> 4;
    const int c = blockIdx.x & 15;
    const int wave = tid >> 6;
    const int lane = tid & 63;
    const int g = lane >> 3;       // row group 0..7
    const int j = lane & 7;        // lane within row

    // v2 fragment for this lane: floats [i*32 + j*4, +4), i = 0..3
    const float4* __restrict__ v2p = reinterpret_cast<const float4*>(v2 + (size_t)b * D_);
    float4 x0 = v2p[j];
    float4 x1 = v2p[j + 8];
    float4 x2 = v2p[j + 16];
    float4 x3 = v2p[j + 24];

    const int* __restrict__ idxb = idx + (size_t)b * KP_ + P_ + (c << 8) + (wave << 6) + g;
    float* __restrict__ outb = out + (size_t)b * OC_ + P2_ + (c << 8) + (wave << 6) + g;

    double de = 0.0;
#pragma unroll
    for (int t = 0; t < 8; t += 2) {
      const int row0 = idxb[t * 8];
      const int row1 = idxb[t * 8 + 8];
      const float4* __restrict__ p0 = reinterpret_cast<const float4*>(mem1 + (size_t)row0 * D_);
      const float4* __restrict__ p1 = reinterpret_cast<const float4*>(mem1 + (size_t)row1 * D_);
      const float4 a0 = p0[j], a1 = p0[j + 8], a2 = p0[j + 16], a3 = p0[j + 24];
      const float4 b0 = p1[j], b1 = p1[j + 8], b2 = p1[j + 16], b3 = p1[j + 24];
      float s0 = a0.x * x0.x + a0.y * x0.y + a0.z * x0.z + a0.w * x0.w
               + a1.x * x1.x + a1.y * x1.y + a1.z * x1.z + a1.w * x1.w
               + a2.x * x2.x + a2.y * x2.y + a2.z * x2.z + a2.w * x2.w
               + a3.x * x3.x + a3.y * x3.y + a3.z * x3.z + a3.w * x3.w;
      float s1 = b0.x * x0.x + b0.y * x0.y + b0.z * x0.z + b0.w * x0.w
               + b1.x * x1.x + b1.y * x1.y + b1.z * x1.z + b1.w * x1.w
               + b2.x * x2.x + b2.y * x2.y + b2.z * x2.z + b2.w * x2.w
               + b3.x * x3.x + b3.y * x3.y + b3.z * x3.z + b3.w * x3.w;
#pragma unroll
      for (int sh = 1; sh < 8; sh <<= 1) {
        s0 += __shfl_xor(s0, sh);
        s1 += __shfl_xor(s1, sh);
      }
      if (j == 0) {
        const float e0 = expf(s0 * (1.0f / T_));
        const float e1 = expf(s1 * (1.0f / T_));
        outb[t * 8] = e0;
        outb[t * 8 + 8] = e1;
        de += (double)e0 + (double)e1;
      }
    }
    // block sum of e (f64) -> wpart[blockIdx]; non-(j==0) lanes hold 0
#pragma unroll
    for (int sh = 1; sh < 64; sh <<= 1) de += __shfl_xor(de, sh);
    __shared__ double lacc[4];
    if (lane == 0) lacc[wave] = de;
    __syncthreads();
    if (tid == 0) wpart[blockIdx.x] = (lacc[0] + lacc[1]) + (lacc[2] + lacc[3]);
  } else {
    __shared__ float sbuf[2 * D_];
    const int b = blockIdx.x - NNEG_;
    if (tid < 32)
      reinterpret_cast<float4*>(sbuf)[tid] =             // sbuf[0..127] = v2[b]
          reinterpret_cast<const float4*>(v2 + (size_t)b * D_)[tid];
    else if (tid < 64)
      reinterpret_cast<float4*>(sbuf)[tid] =             // sbuf[128..255] = v1[b]
          reinterpret_cast<const float4*>(v1 + (size_t)b * D_)[tid - 32];
    __syncthreads();
    if (tid < P_) {
      double n2 = 0.0, n1 = 0.0;
#pragma unroll 8
      for (int jj = 0; jj < D_; ++jj) {
        n2 += (double)sbuf[jj] * sbuf[jj];
        n1 += (double)sbuf[D_ + jj] * sbuf[D_ + jj];
      }
      const double inv_n1 = 1.0 / sqrt(n1);
      const double inv_n2 = 1.0 / sqrt(n2);
      const int row = idx[(size_t)b * KP_ + tid];
      const float4* __restrict__ w1p = reinterpret_cast<const float4*>(mem1 + (size_t)row * D_);
      const float4* __restrict__ w2p = reinterpret_cast<const float4*>(mem2 + (size_t)row * D_);
      const float4* __restrict__ x2p = reinterpret_cast<const float4*>(sbuf);
      const float4* __restrict__ x1p = reinterpret_cast<const float4*>(sbuf + D_);
      double so = 0, sn1 = 0, st = 0, sn2 = 0, ss = 0;
#pragma unroll 4
      for (int jj = 0; jj < 32; ++jj) {
        const float4 a  = w1p[jj];
        const float4 cc = w2p[jj];
        const float4 y1 = x1p[jj];
        const float4 y2 = x2p[jj];
        so  += (double)a.x * y2.x + (double)a.y * y2.y + (double)a.z * y2.z + (double)a.w * y2.w;
        sn1 += (double)a.x * a.x  + (double)a.y * a.y  + (double)a.z * a.z  + (double)a.w * a.w;
        st  += (double)a.x * y1.x + (double)a.y * y1.y + (double)a.z * y1.z + (double)a.w * y1.w;
        sn2 += (double)cc.x * cc.x + (double)cc.y * cc.y + (double)cc.z * cc.z + (double)cc.w * cc.w;
        ss  += (double)cc.x * y2.x + (double)cc.y * y2.y + (double)cc.z * y2.z + (double)cc.w * y2.w;
      }
      const double t_rel = st * inv_n1 / sqrt(sn1);
      const double s_rel = ss * inv_n2 / sqrt(sn2);
      wdiff[b * P_ + tid] = t_rel - s_rel;
      woutp[b * P_ + tid] = expf((float)(so * (1.0 / (double)T_)));
    }
  }
}

// ---------------- kernel 2: stable top-10 selection per row ----------------
// jnp.argsort(-diff) is stable: descending value, ties -> smaller index first.
// Iterative argmax with strict '>' reproduces that exactly.
__global__ __launch_bounds__(128) void k_select(
    const double* __restrict__ wdiff, const float* __restrict__ woutp,
    float* __restrict__ out, double* __restrict__ wpart)
{
  __shared__ double sdiff[P_];
  const int b = blockIdx.x;
  const int tid = threadIdx.x;
  if (tid < P_) sdiff[tid] = wdiff[b * P_ + tid];
  __syncthreads();
  if (tid == 0) {
    unsigned long long lo = 0ull, hi = 0ull;  // taken bitmask (100 bits)
    int sel[P2_];
#pragma unroll
    for (int t = 0; t < P2_; ++t) {
      double best = -1e300;
      int bj = 0;
      for (int j = 0; j < P_; ++j) {
        const bool tk = (j < 64) ? ((lo >> j) & 1ull) : ((hi >> (j - 64)) & 1ull);
        const double v = sdiff[j];
        if (!tk && v > best) { best = v; bj = j; }
      }
      sel[t] = bj;
      if (bj < 64) lo |= (1ull << bj); else hi |= (1ull << (bj - 64));
    }
    sel[0] = 0;  // .at[:,0].set(0) applied AFTER taking top-P2
    double sp = 0.0;
#pragma unroll
    for (int t = 0; t < P2_; ++t) {
      const float e = woutp[b * P_ + sel[t]];
      out[(size_t)b * OC_ + t] = e;  // unnormalized
      sp += (double)e;
    }
    wpart[NNEG_ + b] = sp;
  }
}

// ---------------- kernel 3: reduce partials -> 1/Z ----------------
__global__ __launch_bounds__(256) void k_z(
    const double* __restrict__ wpart, float* __restrict__ invz)
{
  __shared__ double lds[4];
  const int tid = threadIdx.x;
  double s = 0.0;
  for (int i = tid; i < NPART_; i += 256) s += wpart[i];
#pragma unroll
  for (int sh = 1; sh < 64; sh <<= 1) s += __shfl_xor(s, sh);
  if ((tid & 63) == 0) lds[tid >> 6] = s;
  __syncthreads();
  if (tid == 0) {
    const double S = (lds[0] + lds[1]) + (lds[2] + lds[3]);
    const double Z = S / ((double)B_ * (double)OC_) * (double)N_;
    *invz = (float)(1.0 / Z);
  }
}

// ---------------- kernel 4: scale score region by 1/Z ----------------
__global__ __launch_bounds__(256) void k_scale(
    float* __restrict__ out, const float* __restrict__ invz)
{
  const size_t i = (size_t)blockIdx.x * blockDim.x + threadIdx.x;
  constexpr size_t n4 = (size_t)B_ * OC_ / 4;  // 262784, exact
  if (i < n4) {
    const float sc = *invz;
    float4 v = reinterpret_cast<float4*>(out)[i];
    v.x *= sc; v.y *= sc; v.z *= sc; v.w *= sc;
    reinterpret_cast<float4*>(out)[i] = v;
  }
}

// ---------------- kernel 5: copy memory_v1 -> output ----------------
__global__ __launch_bounds__(256) void k_copy(
    const float* __restrict__ src, float* __restrict__ dst)
{
  const size_t i = ((size_t)blockIdx.x * blockDim.x + threadIdx.x) * 4;
  const float4 v = *reinterpret_cast<const float4*>(src + i);
  *reinterpret_cast<float4*>(dst + i) = v;
}

// ---------------- kernel 6: update + normalize rows y ----------------
__global__ __launch_bounds__(64) void k_update(
    const float* __restrict__ mem1, const float* __restrict__ v1,
    const int* __restrict__ y, float* __restrict__ dst)
{
  const int b = blockIdx.x;
  const int lane = threadIdx.x;
  const int row = y[b];
  const float2 m = *reinterpret_cast<const float2*>(mem1 + (size_t)row * D_ + lane * 2);
  const float2 a = *reinterpret_cast<const float2*>(v1 + (size_t)b * D_ + lane * 2);
  float2 l;
  l.x = m.x * 0.5f + a.x * 0.5f;
  l.y = m.y * 0.5f + a.y * 0.5f;
  float n = l.x * l.x + l.y * l.y;
#pragma unroll
  for (int sh = 1; sh < 64; sh <<= 1) n += __shfl_xor(n, sh);
  const float inv = 1.0f / sqrtf(n);
  float2 o;
  o.x = l.x * inv;
  o.y = l.y * inv;
  *reinterpret_cast<float2*>(dst + (size_t)row * D_ + lane * 2) = o;
}

extern "C" void kernel_launch(void* const* d_in, const int* in_sizes, int n_in,
                              void* d_out, int out_size, void* d_ws, size_t ws_size,
                              hipStream_t stream) {
  // setup_inputs order: epoch, v1, v2, y, idx, memory_v1, memory_v2
  const float* v1   = (const float*)d_in[1];
  const float* v2   = (const float*)d_in[2];
  const int*   y    = (const int*)d_in[3];
  const int*   idx  = (const int*)d_in[4];
  const float* mem1 = (const float*)d_in[5];
  const float* mem2 = (const float*)d_in[6];

  float* out    = (float*)d_out;                      // (B, P2+K) scores
  float* outmem = out + (size_t)B_ * OC_;             // (N, D) new memory

  char* ws = (char*)d_ws;
  double* wpart = (double*)ws;                                   // NPART_ doubles
  double* wdiff = (double*)(ws + 65536);                         // B*P doubles = 204,800 B
  float*  woutp = (float*)(ws + 65536 + 204800);                 // B*P floats  = 102,400 B
  float*  invz  = (float*)(ws + 65536 + 204800 + 102400);        // 1 float

  k_gather<<<NNEG_ + B_, 256, 0, stream>>>(v1, v2, idx, mem1, mem2,
                                           out, wdiff, woutp, wpart);
  k_select<<<B_, 128, 0, stream>>>(wdiff, woutp, out, wpart);
  k_z<<<1, 256, 0, stream>>>(wpart, invz);
  {
    constexpr int n4 = B_ * OC_ / 4;
    k_scale<<<(n4 + 255) / 256, 256, 0, stream>>>(out, invz);
  }
  k_copy<<<(N_ * D_) / (256 * 4), 256, 0, stream>>>(mem1, outmem);  // 8192 blocks
  k_update<<<B_, 64, 0, stream>>>(mem1, v1, y, outmem);
}

// Round 4
// 86.575 us; speedup vs baseline: 3.5708x; 1.7318x over previous
//
#include <hip/hip_runtime.h>
#include <math.h>

constexpr int B_ = 256;
constexpr int D_ = 128;
constexpr int N_ = 65536;
constexpr int P_ = 100;
constexpr int K_ = 4096;
constexpr int P2_ = 10;
constexpr int KP_ = K_ + P_;       // 4196
constexpr int OC_ = P2_ + K_;      // 4106
constexpr int NBIN_ = 8;           // row>>13 -> 8 bins of 4 MB (one XCD L2 each)
constexpr int GK_ = B_ * NBIN_;    // 2048 gather blocks
constexpr int NPART_ = GK_ + B_;   // partial-sum slots
constexpr float T_ = 0.07f;

// ---------------- kernel 1: binned gathered dots ----------------
// Blocks [0, GK_): negatives. bin = blk & 7 (aligns with round-robin
//   blockIdx->XCD dispatch), b = blk >> 3. Scan idx[b] coalesced, compact
//   in-bin k's to LDS, then 8-lane-per-row dots: every XCD touches only its
//   4 MB row-range slice -> L2-resident gather.
// Blocks [GK_, GK_+B_): cosine path for r < P, 1 row/thread, f64 dots.
__global__ __launch_bounds__(256) void k_gather(
    const float* __restrict__ v1, const float* __restrict__ v2,
    const int* __restrict__ idx, const float* __restrict__ mem1,
    const float* __restrict__ mem2, float* __restrict__ out,
    double* __restrict__ wdiff, float* __restrict__ woutp,
    double* __restrict__ wpart)
{
  const int tid = threadIdx.x;
  if (blockIdx.x < GK_) {
    const int bin = blockIdx.x & 7;
    const int b   = blockIdx.x >> 3;
    __shared__ unsigned short kcomp[K_];
    __shared__ int cnt;
    __shared__ double lacc[4];
    if (tid == 0) cnt = 0;
    __syncthreads();
    const int* __restrict__ idxb = idx + (size_t)b * KP_ + P_;
#pragma unroll
    for (int i = 0; i < K_ / 256; ++i) {          // 16 coalesced sweeps
      const int k = (i << 8) + tid;
      const int row = idxb[k];
      if ((row >> 13) == bin) {
        const int slot = atomicAdd(&cnt, 1);
        kcomp[slot] = (unsigned short)k;
      }
    }
    __syncthreads();
    const int count = cnt;

    const int j  = tid & 7;    // lane within row
    const int gg = tid >> 3;   // row group 0..31 (block-wide)
    const float4* __restrict__ v2p = reinterpret_cast<const float4*>(v2 + (size_t)b * D_);
    const float4 x0 = v2p[j], x1 = v2p[j + 8], x2 = v2p[j + 16], x3 = v2p[j + 24];
    float* __restrict__ outb = out + (size_t)b * OC_ + P2_;

    double de = 0.0;
    int s = gg;
    for (; s + 32 < count; s += 64) {             // 2 rows in flight per group
      const int k0 = kcomp[s];
      const int k1 = kcomp[s + 32];
      const int row0 = idxb[k0];
      const int row1 = idxb[k1];
      const float4* __restrict__ p0 = reinterpret_cast<const float4*>(mem1 + (size_t)row0 * D_);
      const float4* __restrict__ p1 = reinterpret_cast<const float4*>(mem1 + (size_t)row1 * D_);
      const float4 a0 = p0[j], a1 = p0[j + 8], a2 = p0[j + 16], a3 = p0[j + 24];
      const float4 b0 = p1[j], b1 = p1[j + 8], b2 = p1[j + 16], b3 = p1[j + 24];
      float s0 = a0.x * x0.x + a0.y * x0.y + a0.z * x0.z + a0.w * x0.w
               + a1.x * x1.x + a1.y * x1.y + a1.z * x1.z + a1.w * x1.w
               + a2.x * x2.x + a2.y * x2.y + a2.z * x2.z + a2.w * x2.w
               + a3.x * x3.x + a3.y * x3.y + a3.z * x3.z + a3.w * x3.w;
      float s1 = b0.x * x0.x + b0.y * x0.y + b0.z * x0.z + b0.w * x0.w
               + b1.x * x1.x + b1.y * x1.y + b1.z * x1.z + b1.w * x1.w
               + b2.x * x2.x + b2.y * x2.y + b2.z * x2.z + b2.w * x2.w
               + b3.x * x3.x + b3.y * x3.y + b3.z * x3.z + b3.w * x3.w;
#pragma unroll
      for (int sh = 1; sh < 8; sh <<= 1) {
        s0 += __shfl_xor(s0, sh);
        s1 += __shfl_xor(s1, sh);
      }
      if (j == 0) {
        const float e0 = expf(s0 * (1.0f / T_));
        const float e1 = expf(s1 * (1.0f / T_));
        outb[k0] = e0;
        outb[k1] = e1;
        de += (double)e0 + (double)e1;
      }
    }
    for (; s < count; s += 32) {                  // tail
      const int k0 = kcomp[s];
      const int row0 = idxb[k0];
      const float4* __restrict__ p0 = reinterpret_cast<const float4*>(mem1 + (size_t)row0 * D_);
      const float4 a0 = p0[j], a1 = p0[j + 8], a2 = p0[j + 16], a3 = p0[j + 24];
      float s0 = a0.x * x0.x + a0.y * x0.y + a0.z * x0.z + a0.w * x0.w
               + a1.x * x1.x + a1.y * x1.y + a1.z * x1.z + a1.w * x1.w
               + a2.x * x2.x + a2.y * x2.y + a2.z * x2.z + a2.w * x2.w
               + a3.x * x3.x + a3.y * x3.y + a3.z * x3.z + a3.w * x3.w;
#pragma unroll
      for (int sh = 1; sh < 8; sh <<= 1) s0 += __shfl_xor(s0, sh);
      if (j == 0) {
        const float e0 = expf(s0 * (1.0f / T_));
        outb[k0] = e0;
        de += (double)e0;
      }
    }
#pragma unroll
    for (int sh = 1; sh < 64; sh <<= 1) de += __shfl_xor(de, sh);
    if ((tid & 63) == 0) lacc[tid >> 6] = de;
    __syncthreads();
    if (tid == 0) wpart[blockIdx.x] = (lacc[0] + lacc[1]) + (lacc[2] + lacc[3]);
  } else {
    __shared__ float sbuf[2 * D_];
    const int b = blockIdx.x - GK_;
    if (tid < 32)
      reinterpret_cast<float4*>(sbuf)[tid] =             // sbuf[0..127] = v2[b]
          reinterpret_cast<const float4*>(v2 + (size_t)b * D_)[tid];
    else if (tid < 64)
      reinterpret_cast<float4*>(sbuf)[tid] =             // sbuf[128..255] = v1[b]
          reinterpret_cast<const float4*>(v1 + (size_t)b * D_)[tid - 32];
    __syncthreads();
    if (tid < P_) {
      double n2 = 0.0, n1 = 0.0;
#pragma unroll 8
      for (int jj = 0; jj < D_; ++jj) {
        n2 += (double)sbuf[jj] * sbuf[jj];
        n1 += (double)sbuf[D_ + jj] * sbuf[D_ + jj];
      }
      const double inv_n1 = 1.0 / sqrt(n1);
      const double inv_n2 = 1.0 / sqrt(n2);
      const int row = idx[(size_t)b * KP_ + tid];
      const float4* __restrict__ w1p = reinterpret_cast<const float4*>(mem1 + (size_t)row * D_);
      const float4* __restrict__ w2p = reinterpret_cast<const float4*>(mem2 + (size_t)row * D_);
      const float4* __restrict__ x2p = reinterpret_cast<const float4*>(sbuf);
      const float4* __restrict__ x1p = reinterpret_cast<const float4*>(sbuf + D_);
      double so = 0, sn1 = 0, st = 0, sn2 = 0, ss = 0;
#pragma unroll 4
      for (int jj = 0; jj < 32; ++jj) {
        const float4 a  = w1p[jj];
        const float4 cc = w2p[jj];
        const float4 y1 = x1p[jj];
        const float4 y2 = x2p[jj];
        so  += (double)a.x * y2.x + (double)a.y * y2.y + (double)a.z * y2.z + (double)a.w * y2.w;
        sn1 += (double)a.x * a.x  + (double)a.y * a.y  + (double)a.z * a.z  + (double)a.w * a.w;
        st  += (double)a.x * y1.x + (double)a.y * y1.y + (double)a.z * y1.z + (double)a.w * y1.w;
        sn2 += (double)cc.x * cc.x + (double)cc.y * cc.y + (double)cc.z * cc.z + (double)cc.w * cc.w;
        ss  += (double)cc.x * y2.x + (double)cc.y * y2.y + (double)cc.z * y2.z + (double)cc.w * y2.w;
      }
      const double t_rel = st * inv_n1 / sqrt(sn1);
      const double s_rel = ss * inv_n2 / sqrt(sn2);
      wdiff[b * P_ + tid] = t_rel - s_rel;
      woutp[b * P_ + tid] = expf((float)(so * (1.0 / (double)T_)));
    }
  }
}

// ---------------- kernel 2: stable top-10 selection (wave-parallel) ----------
// jnp.argsort(-diff) is stable: descending value, ties -> smaller index first.
// Butterfly argmax under lexicographic (value desc, index asc) order.
__global__ __launch_bounds__(64) void k_select(
    const double* __restrict__ wdiff, const float* __restrict__ woutp,
    float* __restrict__ out, double* __restrict__ wpart)
{
  const int b = blockIdx.x;
  const int l = threadIdx.x;  // 0..63
  const double* __restrict__ db = wdiff + b * P_;
  const double va = db[l];                                   // j = l
  const double vb = (l < P_ - 64) ? db[l + 64] : -1.0e300;   // j = l + 64
  bool ta = false, tb = (l >= P_ - 64);
  int sel[P2_];
#pragma unroll
  for (int t = 0; t < P2_; ++t) {
    double cv; int cj;
    const bool aok = !ta, bok = !tb;
    if (aok && (!bok || va >= vb)) { cv = va; cj = l; }       // tie -> smaller j
    else if (bok)                  { cv = vb; cj = l + 64; }
    else                           { cv = -1.0e300; cj = 0x7fffffff; }
#pragma unroll
    for (int sh = 1; sh < 64; sh <<= 1) {
      const double ov = __shfl_xor(cv, sh);
      const int    oj = __shfl_xor(cj, sh);
      if (ov > cv || (ov == cv && oj < cj)) { cv = ov; cj = oj; }
    }
    sel[t] = cj;
    if (cj == l) ta = true;
    if (cj == l + 64) tb = true;
  }
  if (l == 0) {
    sel[0] = 0;  // .at[:,0].set(0) applied AFTER taking top-P2
    double sp = 0.0;
#pragma unroll
    for (int t = 0; t < P2_; ++t) {
      const float e = woutp[b * P_ + sel[t]];
      out[(size_t)b * OC_ + t] = e;  // unnormalized
      sp += (double)e;
    }
    wpart[GK_ + b] = sp;
  }
}

// ---------------- kernel 3: reduce partials -> 1/Z ----------------
__global__ __launch_bounds__(256) void k_z(
    const double* __restrict__ wpart, float* __restrict__ invz)
{
  __shared__ double lds[4];
  const int tid = threadIdx.x;
  double s = 0.0;
  for (int i = tid; i < NPART_; i += 256) s += wpart[i];
#pragma unroll
  for (int sh = 1; sh < 64; sh <<= 1) s += __shfl_xor(s, sh);
  if ((tid & 63) == 0) lds[tid >> 6] = s;
  __syncthreads();
  if (tid == 0) {
    const double S = (lds[0] + lds[1]) + (lds[2] + lds[3]);
    const double Z = S / ((double)B_ * (double)OC_) * (double)N_;
    *invz = (float)(1.0 / Z);
  }
}

// ---------------- kernel 4: scale score region by 1/Z ----------------
__global__ __launch_bounds__(256) void k_scale(
    float* __restrict__ out, const float* __restrict__ invz)
{
  const size_t i = (size_t)blockIdx.x * blockDim.x + threadIdx.x;
  constexpr size_t n4 = (size_t)B_ * OC_ / 4;  // 262784, exact
  if (i < n4) {
    const float sc = *invz;
    float4 v = reinterpret_cast<float4*>(out)[i];
    v.x *= sc; v.y *= sc; v.z *= sc; v.w *= sc;
    reinterpret_cast<float4*>(out)[i] = v;
  }
}

// ---------------- kernel 5: copy memory_v1 -> output ----------------
__global__ __launch_bounds__(256) void k_copy(
    const float* __restrict__ src, float* __restrict__ dst)
{
  const size_t i = ((size_t)blockIdx.x * blockDim.x + threadIdx.x) * 4;
  const float4 v = *reinterpret_cast<const float4*>(src + i);
  *reinterpret_cast<float4*>(dst + i) = v;
}

// ---------------- kernel 6: update + normalize rows y ----------------
__global__ __launch_bounds__(64) void k_update(
    const float* __restrict__ mem1, const float* __restrict__ v1,
    const int* __restrict__ y, float* __restrict__ dst)
{
  const int b = blockIdx.x;
  const int lane = threadIdx.x;
  const int row = y[b];
  const float2 m = *reinterpret_cast<const float2*>(mem1 + (size_t)row * D_ + lane * 2);
  const float2 a = *reinterpret_cast<const float2*>(v1 + (size_t)b * D_ + lane * 2);
  float2 l;
  l.x = m.x * 0.5f + a.x * 0.5f;
  l.y = m.y * 0.5f + a.y * 0.5f;
  float n = l.x * l.x + l.y * l.y;
#pragma unroll
  for (int sh = 1; sh < 64; sh <<= 1) n += __shfl_xor(n, sh);
  const float inv = 1.0f / sqrtf(n);
  float2 o;
  o.x = l.x * inv;
  o.y = l.y * inv;
  *reinterpret_cast<float2*>(dst + (size_t)row * D_ + lane * 2) = o;
}

extern "C" void kernel_launch(void* const* d_in, const int* in_sizes, int n_in,
                              void* d_out, int out_size, void* d_ws, size_t ws_size,
                              hipStream_t stream) {
  // setup_inputs order: epoch, v1, v2, y, idx, memory_v1, memory_v2
  const float* v1   = (const float*)d_in[1];
  const float* v2   = (const float*)d_in[2];
  const int*   y    = (const int*)d_in[3];
  const int*   idx  = (const int*)d_in[4];
  const float* mem1 = (const float*)d_in[5];
  const float* mem2 = (const float*)d_in[6];

  float* out    = (float*)d_out;                      // (B, P2+K) scores
  float* outmem = out + (size_t)B_ * OC_;             // (N, D) new memory

  char* ws = (char*)d_ws;
  double* wpart = (double*)ws;                                   // NPART_ doubles
  double* wdiff = (double*)(ws + 65536);                         // B*P doubles = 204,800 B
  float*  woutp = (float*)(ws + 65536 + 204800);                 // B*P floats  = 102,400 B
  float*  invz  = (float*)(ws + 65536 + 204800 + 102400);        // 1 float

  k_gather<<<GK_ + B_, 256, 0, stream>>>(v1, v2, idx, mem1, mem2,
                                         out, wdiff, woutp, wpart);
  k_select<<<B_, 64, 0, stream>>>(wdiff, woutp, out, wpart);
  k_z<<<1, 256, 0, stream>>>(wpart, invz);
  {
    constexpr int n4 = B_ * OC_ / 4;
    k_scale<<<(n4 + 255) / 256, 256, 0, stream>>>(out, invz);
  }
  k_copy<<<(N_ * D_) / (256 * 4), 256, 0, stream>>>(mem1, outmem);  // 8192 blocks
  k_update<<<B_, 64, 0, stream>>>(mem1, v1, y, outmem);
}

// Round 5
// 73.743 us; speedup vs baseline: 4.1921x; 1.1740x over previous
//
#include <hip/hip_runtime.h>
#include <math.h>

constexpr int B_ = 256;
constexpr int D_ = 128;
constexpr int N_ = 65536;
constexpr int P_ = 100;
constexpr int K_ = 4096;
constexpr int P2_ = 10;
constexpr int KP_ = K_ + P_;       // 4196
constexpr int OC_ = P2_ + K_;      // 4106
constexpr int NBIN_ = 8;           // row>>13 -> 8 bins of 4 MB (one XCD L2 each)
constexpr int SLOT_ = 768;         // capacity per (b,bin); mean 512, sd 21 -> 12 sd slack
constexpr int GCOPY_ = 2048;       // copy blocks   [0, 2048)
constexpr int GGATH_ = B_ * NBIN_; // gather blocks [2048, 4096)
constexpr int GCOS_ = B_;          // cos+select    [4096, 4352)
constexpr int NPART_ = GGATH_ + B_;
constexpr float T_ = 0.07f;

// ---------------- kernel 0: bin the negatives' indices ----------------
// One block per b: scan idx[b][P..P+K) once (int4 coalesced), pack
// (k<<16)|row into per-(b,bin) lists. Removes the 8x-redundant scan from
// the gather blocks entirely.
__global__ __launch_bounds__(256) void k_bin(
    const int* __restrict__ idx, unsigned* __restrict__ lists,
    int* __restrict__ counts)
{
  const int b = blockIdx.x;
  const int tid = threadIdx.x;
  __shared__ int cnt[NBIN_];
  if (tid < NBIN_) cnt[tid] = 0;
  __syncthreads();
  // byte offset (b*4196+100)*4 is 16B-aligned for all b
  const int4* __restrict__ src = reinterpret_cast<const int4*>(idx + (size_t)b * KP_ + P_);
#pragma unroll
  for (int i = 0; i < 4; ++i) {
    const int4 r4 = src[i * 256 + tid];
    const int ks = (i * 256 + tid) * 4;
    const int rows[4] = {r4.x, r4.y, r4.z, r4.w};
#pragma unroll
    for (int u = 0; u < 4; ++u) {
      const int row = rows[u];
      const int bin = row >> 13;
      const int slot = atomicAdd(&cnt[bin], 1);
      if (slot < SLOT_)
        lists[((size_t)(b * NBIN_ + bin)) * SLOT_ + slot] =
            ((unsigned)(ks + u) << 16) | (unsigned)row;
    }
  }
  __syncthreads();
  if (tid < NBIN_) counts[b * NBIN_ + tid] = min(cnt[tid], SLOT_);
}

// ---------------- kernel 1: fused copy + binned gather + cos/select -------
__global__ __launch_bounds__(256) void k_main(
    const float* __restrict__ v1, const float* __restrict__ v2,
    const int* __restrict__ idx, const float* __restrict__ mem1,
    const float* __restrict__ mem2, const unsigned* __restrict__ lists,
    const int* __restrict__ counts, float* __restrict__ out,
    float* __restrict__ outmem, double* __restrict__ wpart)
{
  const int tid = threadIdx.x;
  const unsigned bid = blockIdx.x;
  __shared__ double lacc[4];
  __shared__ float sbuf[2 * D_];
  __shared__ double sdiff[P_];
  __shared__ float swout[P_];

  if (bid < GCOPY_) {
    // ---- copy memory_v1 -> outmem, bin-aligned: blockIdx%8 == rows' bin ----
    const int r = bid & 7, q = bid >> 3;
    const size_t base = ((size_t)r * 8192 + (size_t)q * 32) * D_;  // 32 rows = 16 KB
    const float4* __restrict__ s = reinterpret_cast<const float4*>(mem1 + base);
    float4* __restrict__ d = reinterpret_cast<float4*>(outmem + base);
#pragma unroll
    for (int i = 0; i < 4; ++i) d[i * 256 + tid] = s[i * 256 + tid];
  } else if (bid < GCOPY_ + GGATH_) {
    // ---- binned gather dots: 8 lanes per row, rows from prebuilt list ----
    const int g = bid - GCOPY_;
    const int bin = g & 7, b = g >> 3;
    const int count = counts[b * NBIN_ + bin];
    const unsigned* __restrict__ lb = lists + ((size_t)(b * NBIN_ + bin)) * SLOT_;
    const int j = tid & 7, gg = tid >> 3;
    const float4* __restrict__ v2p = reinterpret_cast<const float4*>(v2 + (size_t)b * D_);
    const float4 x0 = v2p[j], x1 = v2p[j + 8], x2 = v2p[j + 16], x3 = v2p[j + 24];
    float* __restrict__ outb = out + (size_t)b * OC_ + P2_;

    double de = 0.0;
    int s = gg;
    for (; s + 32 < count; s += 64) {             // 2 rows in flight per group
      const unsigned e0 = lb[s];
      const unsigned e1 = lb[s + 32];
      const float4* __restrict__ p0 = reinterpret_cast<const float4*>(mem1 + (size_t)(e0 & 0xFFFFu) * D_);
      const float4* __restrict__ p1 = reinterpret_cast<const float4*>(mem1 + (size_t)(e1 & 0xFFFFu) * D_);
      const float4 a0 = p0[j], a1 = p0[j + 8], a2 = p0[j + 16], a3 = p0[j + 24];
      const float4 b0 = p1[j], b1 = p1[j + 8], b2 = p1[j + 16], b3 = p1[j + 24];
      float s0 = a0.x * x0.x + a0.y * x0.y + a0.z * x0.z + a0.w * x0.w
               + a1.x * x1.x + a1.y * x1.y + a1.z * x1.z + a1.w * x1.w
               + a2.x * x2.x + a2.y * x2.y + a2.z * x2.z + a2.w * x2.w
               + a3.x * x3.x + a3.y * x3.y + a3.z * x3.z + a3.w * x3.w;
      float s1 = b0.x * x0.x + b0.y * x0.y + b0.z * x0.z + b0.w * x0.w
               + b1.x * x1.x + b1.y * x1.y + b1.z * x1.z + b1.w * x1.w
               + b2.x * x2.x + b2.y * x2.y + b2.z * x2.z + b2.w * x2.w
               + b3.x * x3.x + b3.y * x3.y + b3.z * x3.z + b3.w * x3.w;
#pragma unroll
      for (int sh = 1; sh < 8; sh <<= 1) {
        s0 += __shfl_xor(s0, sh);
        s1 += __shfl_xor(s1, sh);
      }
      if (j == 0) {
        const float e0f = expf(s0 * (1.0f / T_));
        const float e1f = expf(s1 * (1.0f / T_));
        outb[e0 >> 16] = e0f;
        outb[e1 >> 16] = e1f;
        de += (double)e0f + (double)e1f;
      }
    }
    for (; s < count; s += 32) {                  // tail
      const unsigned e0 = lb[s];
      const float4* __restrict__ p0 = reinterpret_cast<const float4*>(mem1 + (size_t)(e0 & 0xFFFFu) * D_);
      const float4 a0 = p0[j], a1 = p0[j + 8], a2 = p0[j + 16], a3 = p0[j + 24];
      float s0 = a0.x * x0.x + a0.y * x0.y + a0.z * x0.z + a0.w * x0.w
               + a1.x * x1.x + a1.y * x1.y + a1.z * x1.z + a1.w * x1.w
               + a2.x * x2.x + a2.y * x2.y + a2.z * x2.z + a2.w * x2.w
               + a3.x * x3.x + a3.y * x3.y + a3.z * x3.z + a3.w * x3.w;
#pragma unroll
      for (int sh = 1; sh < 8; sh <<= 1) s0 += __shfl_xor(s0, sh);
      if (j == 0) {
        const float e0f = expf(s0 * (1.0f / T_));
        outb[e0 >> 16] = e0f;
        de += (double)e0f;
      }
    }
#pragma unroll
    for (int sh = 1; sh < 64; sh <<= 1) de += __shfl_xor(de, sh);
    if ((tid & 63) == 0) lacc[tid >> 6] = de;
    __syncthreads();
    if (tid == 0) wpart[g] = (lacc[0] + lacc[1]) + (lacc[2] + lacc[3]);
  } else {
    // ---- cosine path (r < P) + fused stable top-10 selection ----
    const int b = bid - GCOPY_ - GGATH_;
    if (tid < 32)
      reinterpret_cast<float4*>(sbuf)[tid] =             // sbuf[0..127] = v2[b]
          reinterpret_cast<const float4*>(v2 + (size_t)b * D_)[tid];
    else if (tid < 64)
      reinterpret_cast<float4*>(sbuf)[tid] =             // sbuf[128..255] = v1[b]
          reinterpret_cast<const float4*>(v1 + (size_t)b * D_)[tid - 32];
    __syncthreads();
    if (tid < P_) {
      double n2 = 0.0, n1 = 0.0;
#pragma unroll 8
      for (int jj = 0; jj < D_; ++jj) {
        n2 += (double)sbuf[jj] * sbuf[jj];
        n1 += (double)sbuf[D_ + jj] * sbuf[D_ + jj];
      }
      const double inv_n1 = 1.0 / sqrt(n1);
      const double inv_n2 = 1.0 / sqrt(n2);
      const int row = idx[(size_t)b * KP_ + tid];
      const float4* __restrict__ w1p = reinterpret_cast<const float4*>(mem1 + (size_t)row * D_);
      const float4* __restrict__ w2p = reinterpret_cast<const float4*>(mem2 + (size_t)row * D_);
      const float4* __restrict__ x2p = reinterpret_cast<const float4*>(sbuf);
      const float4* __restrict__ x1p = reinterpret_cast<const float4*>(sbuf + D_);
      double so = 0, sn1 = 0, st = 0, sn2 = 0, ss = 0;
#pragma unroll 4
      for (int jj = 0; jj < 32; ++jj) {
        const float4 a  = w1p[jj];
        const float4 cc = w2p[jj];
        const float4 y1 = x1p[jj];
        const float4 y2 = x2p[jj];
        so  += (double)a.x * y2.x + (double)a.y * y2.y + (double)a.z * y2.z + (double)a.w * y2.w;
        sn1 += (double)a.x * a.x  + (double)a.y * a.y  + (double)a.z * a.z  + (double)a.w * a.w;
        st  += (double)a.x * y1.x + (double)a.y * y1.y + (double)a.z * y1.z + (double)a.w * y1.w;
        sn2 += (double)cc.x * cc.x + (double)cc.y * cc.y + (double)cc.z * cc.z + (double)cc.w * cc.w;
        ss  += (double)cc.x * y2.x + (double)cc.y * y2.y + (double)cc.z * y2.z + (double)cc.w * y2.w;
      }
      const double t_rel = st * inv_n1 / sqrt(sn1);
      const double s_rel = ss * inv_n2 / sqrt(sn2);
      sdiff[tid] = t_rel - s_rel;
      swout[tid] = expf((float)(so * (1.0 / (double)T_)));
    }
    __syncthreads();
    if (tid < 64) {
      // stable top-10: butterfly argmax under (value desc, index asc)
      const int l = tid;
      const double va = sdiff[l];
      const double vb = (l < P_ - 64) ? sdiff[l + 64] : -1.0e300;
      bool ta = false, tb = (l >= P_ - 64);
      int sel[P2_];
#pragma unroll
      for (int t = 0; t < P2_; ++t) {
        double cv; int cj;
        const bool aok = !ta, bok = !tb;
        if (aok && (!bok || va >= vb)) { cv = va; cj = l; }
        else if (bok)                  { cv = vb; cj = l + 64; }
        else                           { cv = -1.0e300; cj = 0x7fffffff; }
#pragma unroll
        for (int sh = 1; sh < 64; sh <<= 1) {
          const double ov = __shfl_xor(cv, sh);
          const int    oj = __shfl_xor(cj, sh);
          if (ov > cv || (ov == cv && oj < cj)) { cv = ov; cj = oj; }
        }
        sel[t] = cj;
        if (cj == l) ta = true;
        if (cj == l + 64) tb = true;
      }
      if (l == 0) {
        sel[0] = 0;  // .at[:,0].set(0) applied AFTER taking top-P2
        double sp = 0.0;
#pragma unroll
        for (int t = 0; t < P2_; ++t) {
          const float e = swout[sel[t]];
          out[(size_t)b * OC_ + t] = e;  // unnormalized
          sp += (double)e;
        }
        wpart[GGATH_ + b] = sp;
      }
    }
  }
}

// ---------------- kernel 2: reduce partials -> 1/Z ----------------
__global__ __launch_bounds__(256) void k_z(
    const double* __restrict__ wpart, float* __restrict__ invz)
{
  __shared__ double lds[4];
  const int tid = threadIdx.x;
  double s = 0.0;
  for (int i = tid; i < NPART_; i += 256) s += wpart[i];
#pragma unroll
  for (int sh = 1; sh < 64; sh <<= 1) s += __shfl_xor(s, sh);
  if ((tid & 63) == 0) lds[tid >> 6] = s;
  __syncthreads();
  if (tid == 0) {
    const double S = (lds[0] + lds[1]) + (lds[2] + lds[3]);
    const double Z = S / ((double)B_ * (double)OC_) * (double)N_;
    *invz = (float)(1.0 / Z);
  }
}

// ---------------- kernel 3: scale scores by 1/Z + y-row update ----------
constexpr int NSC_ = (B_ * OC_ / 4 + 255) / 256;  // 1027 scale blocks
__global__ __launch_bounds__(256) void k_scale_upd(
    float* __restrict__ out, const float* __restrict__ invz,
    const float* __restrict__ mem1, const float* __restrict__ v1,
    const int* __restrict__ y, float* __restrict__ dst)
{
  const int tid = threadIdx.x;
  if (blockIdx.x < NSC_) {
    const size_t i = (size_t)blockIdx.x * 256 + tid;
    constexpr size_t n4 = (size_t)B_ * OC_ / 4;
    if (i < n4) {
      const float sc = *invz;
      float4 v = reinterpret_cast<float4*>(out)[i];
      v.x *= sc; v.y *= sc; v.z *= sc; v.w *= sc;
      reinterpret_cast<float4*>(out)[i] = v;
    }
  } else if (tid < 64) {
    const int b = blockIdx.x - NSC_;
    const int lane = tid;
    const int row = y[b];
    const float2 m = *reinterpret_cast<const float2*>(mem1 + (size_t)row * D_ + lane * 2);
    const float2 a = *reinterpret_cast<const float2*>(v1 + (size_t)b * D_ + lane * 2);
    float2 l;
    l.x = m.x * 0.5f + a.x * 0.5f;
    l.y = m.y * 0.5f + a.y * 0.5f;
    float n = l.x * l.x + l.y * l.y;
#pragma unroll
    for (int sh = 1; sh < 64; sh <<= 1) n += __shfl_xor(n, sh);
    const float inv = 1.0f / sqrtf(n);
    float2 o;
    o.x = l.x * inv;
    o.y = l.y * inv;
    *reinterpret_cast<float2*>(dst + (size_t)row * D_ + lane * 2) = o;
  }
}

extern "C" void kernel_launch(void* const* d_in, const int* in_sizes, int n_in,
                              void* d_out, int out_size, void* d_ws, size_t ws_size,
                              hipStream_t stream) {
  // setup_inputs order: epoch, v1, v2, y, idx, memory_v1, memory_v2
  const float* v1   = (const float*)d_in[1];
  const float* v2   = (const float*)d_in[2];
  const int*   y    = (const int*)d_in[3];
  const int*   idx  = (const int*)d_in[4];
  const float* mem1 = (const float*)d_in[5];
  const float* mem2 = (const float*)d_in[6];

  float* out    = (float*)d_out;                      // (B, P2+K) scores
  float* outmem = out + (size_t)B_ * OC_;             // (N, D) new memory

  char* ws = (char*)d_ws;
  double*   wpart  = (double*)ws;                                // NPART_ doubles (18,432 B)
  int*      counts = (int*)(ws + 32768);                         // B*8 ints (8,192 B)
  unsigned* lists  = (unsigned*)(ws + 65536);                    // B*8*SLOT_ u32 = 6,291,456 B
  float*    invz   = (float*)(ws + 65536 + (size_t)B_ * NBIN_ * SLOT_ * 4);

  k_bin<<<B_, 256, 0, stream>>>(idx, lists, counts);
  k_main<<<GCOPY_ + GGATH_ + GCOS_, 256, 0, stream>>>(
      v1, v2, idx, mem1, mem2, lists, counts, out, outmem, wpart);
  k_z<<<1, 256, 0, stream>>>(wpart, invz);
  k_scale_upd<<<NSC_ + B_, 256, 0, stream>>>(out, invz, mem1, v1, y, outmem);
}

// Round 6
// 65.986 us; speedup vs baseline: 4.6849x; 1.1176x over previous
//
#include <hip/hip_runtime.h>
#include <math.h>

constexpr int B_ = 256;
constexpr int D_ = 128;
constexpr int N_ = 65536;
constexpr int P_ = 100;
constexpr int K_ = 4096;
constexpr int P2_ = 10;
constexpr int KP_ = K_ + P_;       // 4196
constexpr int OC_ = P2_ + K_;      // 4106
constexpr int NBIN_ = 8;           // row>>13 -> 8 bins of 4 MB (one XCD L2 each)
constexpr int SLOT_ = 768;         // capacity per (b,bin); mean 512, sd 21 -> 12 sd slack
constexpr int GCOS_ = B_;          // cos+select  [0, 256)    -- longest pole first
constexpr int GCOPY_ = 2048;       // copy        [256, 2304) -- primes L2 slices
constexpr int GGATH_ = B_ * NBIN_; // gather      [2304, 4352)
constexpr int NPART_ = GGATH_ + B_;
constexpr float T_ = 0.07f;

// ---------------- kernel 0: bin the negatives' indices ----------------
__global__ __launch_bounds__(256) void k_bin(
    const int* __restrict__ idx, unsigned* __restrict__ lists,
    int* __restrict__ counts)
{
  const int b = blockIdx.x;
  const int tid = threadIdx.x;
  __shared__ int cnt[NBIN_];
  if (tid < NBIN_) cnt[tid] = 0;
  __syncthreads();
  const int4* __restrict__ src = reinterpret_cast<const int4*>(idx + (size_t)b * KP_ + P_);
#pragma unroll
  for (int i = 0; i < 4; ++i) {
    const int4 r4 = src[i * 256 + tid];
    const int ks = (i * 256 + tid) * 4;
    const int rows[4] = {r4.x, r4.y, r4.z, r4.w};
#pragma unroll
    for (int u = 0; u < 4; ++u) {
      const int row = rows[u];
      const int bin = row >> 13;
      const int slot = atomicAdd(&cnt[bin], 1);
      if (slot < SLOT_)
        lists[((size_t)(b * NBIN_ + bin)) * SLOT_ + slot] =
            ((unsigned)(ks + u) << 16) | (unsigned)row;
    }
  }
  __syncthreads();
  if (tid < NBIN_) counts[b * NBIN_ + tid] = min(cnt[tid], SLOT_);
}

// -------- kernel 1: fused cos/select + copy + binned gather (dense e) -----
__global__ __launch_bounds__(256) void k_main(
    const float* __restrict__ v1, const float* __restrict__ v2,
    const int* __restrict__ idx, const float* __restrict__ mem1,
    const float* __restrict__ mem2, const unsigned* __restrict__ lists,
    const int* __restrict__ counts, float* __restrict__ evals,
    float* __restrict__ wsel, float* __restrict__ outmem,
    double* __restrict__ wpart)
{
  const int tid = threadIdx.x;
  const unsigned bid = blockIdx.x;
  __shared__ double lacc[4];
  __shared__ float sbuf[2 * D_];
  __shared__ double sdiff[P_];
  __shared__ float swout[P_];
  __shared__ double dsn2[P_], dss[P_];
  __shared__ double dinv[2];

  if (bid < GCOS_) {
    // ---- cosine path: w1-dots on tid<100, w2-dots on tid in [128,228) ----
    const int b = bid;
    if (tid < 32)
      reinterpret_cast<float4*>(sbuf)[tid] =             // sbuf[0..127] = v2[b]
          reinterpret_cast<const float4*>(v2 + (size_t)b * D_)[tid];
    else if (tid < 64)
      reinterpret_cast<float4*>(sbuf)[tid] =             // sbuf[128..255] = v1[b]
          reinterpret_cast<const float4*>(v1 + (size_t)b * D_)[tid - 32];
    __syncthreads();
    if (tid < 64) {                                      // wave-parallel norms
      const float2* s2 = reinterpret_cast<const float2*>(sbuf);
      const float2 a = s2[tid];        // v2 elems
      const float2 c = s2[64 + tid];   // v1 elems
      double dn2 = (double)a.x * a.x + (double)a.y * a.y;
      double dn1 = (double)c.x * c.x + (double)c.y * c.y;
#pragma unroll
      for (int sh = 1; sh < 64; sh <<= 1) {
        dn2 += __shfl_xor(dn2, sh);
        dn1 += __shfl_xor(dn1, sh);
      }
      if (tid == 0) { dinv[0] = 1.0 / sqrt(dn1); dinv[1] = 1.0 / sqrt(dn2); }
    }
    if (tid >= 128 && tid < 128 + P_) {                  // w2: sn2, ss
      const int r = tid - 128;
      const int row = idx[(size_t)b * KP_ + r];
      const float4* __restrict__ w2p = reinterpret_cast<const float4*>(mem2 + (size_t)row * D_);
      const float4* __restrict__ x2p = reinterpret_cast<const float4*>(sbuf);
      double sn2 = 0, ss = 0;
#pragma unroll 4
      for (int jj = 0; jj < 32; ++jj) {
        const float4 cc = w2p[jj];
        const float4 y2 = x2p[jj];
        sn2 += (double)cc.x * cc.x + (double)cc.y * cc.y + (double)cc.z * cc.z + (double)cc.w * cc.w;
        ss  += (double)cc.x * y2.x + (double)cc.y * y2.y + (double)cc.z * y2.z + (double)cc.w * y2.w;
      }
      dsn2[r] = sn2; dss[r] = ss;
    }
    double so = 0, sn1 = 0, st = 0;
    if (tid < P_) {                                      // w1: so, sn1, st
      const int row = idx[(size_t)b * KP_ + tid];
      const float4* __restrict__ w1p = reinterpret_cast<const float4*>(mem1 + (size_t)row * D_);
      const float4* __restrict__ x2p = reinterpret_cast<const float4*>(sbuf);
      const float4* __restrict__ x1p = reinterpret_cast<const float4*>(sbuf + D_);
#pragma unroll 4
      for (int jj = 0; jj < 32; ++jj) {
        const float4 a  = w1p[jj];
        const float4 y1 = x1p[jj];
        const float4 y2 = x2p[jj];
        so  += (double)a.x * y2.x + (double)a.y * y2.y + (double)a.z * y2.z + (double)a.w * y2.w;
        sn1 += (double)a.x * a.x  + (double)a.y * a.y  + (double)a.z * a.z  + (double)a.w * a.w;
        st  += (double)a.x * y1.x + (double)a.y * y1.y + (double)a.z * y1.z + (double)a.w * y1.w;
      }
    }
    __syncthreads();
    if (tid < P_) {
      const double t_rel = st * dinv[0] / sqrt(sn1);
      const double s_rel = dss[tid] * dinv[1] / sqrt(dsn2[tid]);
      sdiff[tid] = t_rel - s_rel;
      swout[tid] = expf((float)(so * (1.0 / (double)T_)));
    }
    __syncthreads();
    if (tid < 64) {
      // stable top-10: butterfly argmax under (value desc, index asc)
      const int l = tid;
      const double va = sdiff[l];
      const double vb = (l < P_ - 64) ? sdiff[l + 64] : -1.0e300;
      bool ta = false, tb = (l >= P_ - 64);
      int sel[P2_];
#pragma unroll
      for (int t = 0; t < P2_; ++t) {
        double cv; int cj;
        const bool aok = !ta, bok = !tb;
        if (aok && (!bok || va >= vb)) { cv = va; cj = l; }
        else if (bok)                  { cv = vb; cj = l + 64; }
        else                           { cv = -1.0e300; cj = 0x7fffffff; }
#pragma unroll
        for (int sh = 1; sh < 64; sh <<= 1) {
          const double ov = __shfl_xor(cv, sh);
          const int    oj = __shfl_xor(cj, sh);
          if (ov > cv || (ov == cv && oj < cj)) { cv = ov; cj = oj; }
        }
        sel[t] = cj;
        if (cj == l) ta = true;
        if (cj == l + 64) tb = true;
      }
      if (l == 0) {
        sel[0] = 0;  // .at[:,0].set(0) applied AFTER taking top-P2
        double sp = 0.0;
#pragma unroll
        for (int t = 0; t < P2_; ++t) {
          const float e = swout[sel[t]];
          wsel[b * P2_ + t] = e;  // unnormalized
          sp += (double)e;
        }
        wpart[GGATH_ + b] = sp;
      }
    }
  } else if (bid < GCOS_ + GCOPY_) {
    // ---- copy memory_v1 -> outmem, bin-aligned (primes L2 slices) ----
    const int g = bid - GCOS_;
    const int r = g & 7, q = g >> 3;
    const size_t base = ((size_t)r * 8192 + (size_t)q * 32) * D_;  // 32 rows = 16 KB
    const float4* __restrict__ s = reinterpret_cast<const float4*>(mem1 + base);
    float4* __restrict__ d = reinterpret_cast<float4*>(outmem + base);
#pragma unroll
    for (int i = 0; i < 4; ++i) d[i * 256 + tid] = s[i * 256 + tid];
  } else {
    // ---- binned gather dots: 8 lanes/row, 4 rows in flight, dense e out ----
    const int g = bid - GCOS_ - GCOPY_;
    const int bin = g & 7, b = g >> 3;
    const int count = counts[b * NBIN_ + bin];
    const unsigned* __restrict__ lb = lists + ((size_t)(b * NBIN_ + bin)) * SLOT_;
    float* __restrict__ eb = evals + ((size_t)(b * NBIN_ + bin)) * SLOT_;
    const int j = tid & 7, gg = tid >> 3;
    const float4* __restrict__ v2p = reinterpret_cast<const float4*>(v2 + (size_t)b * D_);
    const float4 x0 = v2p[j], x1 = v2p[j + 8], x2 = v2p[j + 16], x3 = v2p[j + 24];

    double de = 0.0;
    int s = gg;
    for (; s + 96 < count; s += 128) {            // 4 rows in flight per group
      const unsigned e0 = lb[s];
      const unsigned e1 = lb[s + 32];
      const unsigned e2 = lb[s + 64];
      const unsigned e3 = lb[s + 96];
      const float4* __restrict__ p0 = reinterpret_cast<const float4*>(mem1 + (size_t)(e0 & 0xFFFFu) * D_);
      const float4* __restrict__ p1 = reinterpret_cast<const float4*>(mem1 + (size_t)(e1 & 0xFFFFu) * D_);
      const float4* __restrict__ p2 = reinterpret_cast<const float4*>(mem1 + (size_t)(e2 & 0xFFFFu) * D_);
      const float4* __restrict__ p3 = reinterpret_cast<const float4*>(mem1 + (size_t)(e3 & 0xFFFFu) * D_);
      const float4 a0 = p0[j], a1 = p0[j + 8], a2 = p0[j + 16], a3 = p0[j + 24];
      const float4 b0 = p1[j], b1 = p1[j + 8], b2 = p1[j + 16], b3 = p1[j + 24];
      const float4 c0 = p2[j], c1 = p2[j + 8], c2 = p2[j + 16], c3 = p2[j + 24];
      const float4 d0 = p3[j], d1 = p3[j + 8], d2 = p3[j + 16], d3 = p3[j + 24];
      float s0 = a0.x * x0.x + a0.y * x0.y + a0.z * x0.z + a0.w * x0.w
               + a1.x * x1.x + a1.y * x1.y + a1.z * x1.z + a1.w * x1.w
               + a2.x * x2.x + a2.y * x2.y + a2.z * x2.z + a2.w * x2.w
               + a3.x * x3.x + a3.y * x3.y + a3.z * x3.z + a3.w * x3.w;
      float s1 = b0.x * x0.x + b0.y * x0.y + b0.z * x0.z + b0.w * x0.w
               + b1.x * x1.x + b1.y * x1.y + b1.z * x1.z + b1.w * x1.w
               + b2.x * x2.x + b2.y * x2.y + b2.z * x2.z + b2.w * x2.w
               + b3.x * x3.x + b3.y * x3.y + b3.z * x3.z + b3.w * x3.w;
      float s2v = c0.x * x0.x + c0.y * x0.y + c0.z * x0.z + c0.w * x0.w
                + c1.x * x1.x + c1.y * x1.y + c1.z * x1.z + c1.w * x1.w
                + c2.x * x2.x + c2.y * x2.y + c2.z * x2.z + c2.w * x2.w
                + c3.x * x3.x + c3.y * x3.y + c3.z * x3.z + c3.w * x3.w;
      float s3v = d0.x * x0.x + d0.y * x0.y + d0.z * x0.z + d0.w * x0.w
                + d1.x * x1.x + d1.y * x1.y + d1.z * x1.z + d1.w * x1.w
                + d2.x * x2.x + d2.y * x2.y + d2.z * x2.z + d2.w * x2.w
                + d3.x * x3.x + d3.y * x3.y + d3.z * x3.z + d3.w * x3.w;
#pragma unroll
      for (int sh = 1; sh < 8; sh <<= 1) {
        s0 += __shfl_xor(s0, sh);
        s1 += __shfl_xor(s1, sh);
        s2v += __shfl_xor(s2v, sh);
        s3v += __shfl_xor(s3v, sh);
      }
      if (j == 0) {
        const float f0 = expf(s0 * (1.0f / T_));
        const float f1 = expf(s1 * (1.0f / T_));
        const float f2 = expf(s2v * (1.0f / T_));
        const float f3 = expf(s3v * (1.0f / T_));
        eb[s] = f0; eb[s + 32] = f1; eb[s + 64] = f2; eb[s + 96] = f3;  // dense, coalesced
        de += ((double)f0 + (double)f1) + ((double)f2 + (double)f3);
      }
    }
    for (; s < count; s += 32) {                  // tail
      const unsigned e0 = lb[s];
      const float4* __restrict__ p0 = reinterpret_cast<const float4*>(mem1 + (size_t)(e0 & 0xFFFFu) * D_);
      const float4 a0 = p0[j], a1 = p0[j + 8], a2 = p0[j + 16], a3 = p0[j + 24];
      float s0 = a0.x * x0.x + a0.y * x0.y + a0.z * x0.z + a0.w * x0.w
               + a1.x * x1.x + a1.y * x1.y + a1.z * x1.z + a1.w * x1.w
               + a2.x * x2.x + a2.y * x2.y + a2.z * x2.z + a2.w * x2.w
               + a3.x * x3.x + a3.y * x3.y + a3.z * x3.z + a3.w * x3.w;
#pragma unroll
      for (int sh = 1; sh < 8; sh <<= 1) s0 += __shfl_xor(s0, sh);
      if (j == 0) {
        const float f0 = expf(s0 * (1.0f / T_));
        eb[s] = f0;
        de += (double)f0;
      }
    }
#pragma unroll
    for (int sh = 1; sh < 64; sh <<= 1) de += __shfl_xor(de, sh);
    if ((tid & 63) == 0) lacc[tid >> 6] = de;
    __syncthreads();
    if (tid == 0) wpart[g] = (lacc[0] + lacc[1]) + (lacc[2] + lacc[3]);
  }
}

// ---------------- kernel 2: reduce partials -> 1/Z ----------------
__global__ __launch_bounds__(256) void k_z(
    const double* __restrict__ wpart, float* __restrict__ invz)
{
  __shared__ double lds[4];
  const int tid = threadIdx.x;
  double s = 0.0;
  for (int i = tid; i < NPART_; i += 256) s += wpart[i];
#pragma unroll
  for (int sh = 1; sh < 64; sh <<= 1) s += __shfl_xor(s, sh);
  if ((tid & 63) == 0) lds[tid >> 6] = s;
  __syncthreads();
  if (tid == 0) {
    const double S = (lds[0] + lds[1]) + (lds[2] + lds[3]);
    const double Z = S / ((double)B_ * (double)OC_) * (double)N_;
    *invz = (float)(1.0 / Z);
  }
}

// -------- kernel 3: permute dense e -> out (scaled), + y-row update --------
__global__ __launch_bounds__(256) void k_out(
    const unsigned* __restrict__ lists, const int* __restrict__ counts,
    const float* __restrict__ evals, const float* __restrict__ wsel,
    const float* __restrict__ invz, const float* __restrict__ mem1,
    const float* __restrict__ v1, const int* __restrict__ y,
    float* __restrict__ out, float* __restrict__ outmem)
{
  __shared__ float srow[K_];  // 16 KB
  const int b = blockIdx.x;
  const int tid = threadIdx.x;
  const float sc = *invz;
#pragma unroll
  for (int bin = 0; bin < NBIN_; ++bin) {
    const int cnt = counts[b * NBIN_ + bin];
    const unsigned* __restrict__ lb = lists + ((size_t)(b * NBIN_ + bin)) * SLOT_;
    const float* __restrict__ eb = evals + ((size_t)(b * NBIN_ + bin)) * SLOT_;
    for (int s = tid; s < cnt; s += 256) srow[lb[s] >> 16] = eb[s];
  }
  __syncthreads();
  float* __restrict__ orow = out + (size_t)b * OC_;
  if (tid < P2_) orow[tid] = wsel[b * P2_ + tid] * sc;
  for (int i = tid; i < K_; i += 256) orow[P2_ + i] = srow[i] * sc;
  if (tid < 64) {
    // y-row momentum update + normalize (overwrites copied row)
    const int row = y[b];
    const float2 m = *reinterpret_cast<const float2*>(mem1 + (size_t)row * D_ + tid * 2);
    const float2 a = *reinterpret_cast<const float2*>(v1 + (size_t)b * D_ + tid * 2);
    float2 l;
    l.x = m.x * 0.5f + a.x * 0.5f;
    l.y = m.y * 0.5f + a.y * 0.5f;
    float n = l.x * l.x + l.y * l.y;
#pragma unroll
    for (int sh = 1; sh < 64; sh <<= 1) n += __shfl_xor(n, sh);
    const float inv = 1.0f / sqrtf(n);
    float2 o;
    o.x = l.x * inv;
    o.y = l.y * inv;
    *reinterpret_cast<float2*>(outmem + (size_t)row * D_ + tid * 2) = o;
  }
}

extern "C" void kernel_launch(void* const* d_in, const int* in_sizes, int n_in,
                              void* d_out, int out_size, void* d_ws, size_t ws_size,
                              hipStream_t stream) {
  // setup_inputs order: epoch, v1, v2, y, idx, memory_v1, memory_v2
  const float* v1   = (const float*)d_in[1];
  const float* v2   = (const float*)d_in[2];
  const int*   y    = (const int*)d_in[3];
  const int*   idx  = (const int*)d_in[4];
  const float* mem1 = (const float*)d_in[5];
  const float* mem2 = (const float*)d_in[6];

  float* out    = (float*)d_out;                      // (B, P2+K) scores
  float* outmem = out + (size_t)B_ * OC_;             // (N, D) new memory

  char* ws = (char*)d_ws;
  constexpr size_t LSZ = (size_t)B_ * NBIN_ * SLOT_ * 4;         // 6,291,456 B
  double*   wpart  = (double*)ws;                                // NPART_ doubles
  int*      counts = (int*)(ws + 32768);
  unsigned* lists  = (unsigned*)(ws + 65536);                    // LSZ bytes
  float*    evals  = (float*)(ws + 65536 + LSZ);                 // LSZ bytes
  float*    wsel   = (float*)(ws + 65536 + 2 * LSZ);             // B*P2 floats
  float*    invz   = (float*)(ws + 65536 + 2 * LSZ + 16384);

  k_bin<<<B_, 256, 0, stream>>>(idx, lists, counts);
  k_main<<<GCOS_ + GCOPY_ + GGATH_, 256, 0, stream>>>(
      v1, v2, idx, mem1, mem2, lists, counts, evals, wsel, outmem, wpart);
  k_z<<<1, 256, 0, stream>>>(wpart, invz);
  k_out<<<B_, 256, 0, stream>>>(lists, counts, evals, wsel, invz,
                                mem1, v1, y, out, outmem);
}